// Round 1
// baseline (154.096 us; speedup 1.0000x reference)
//
#include <hip/hip_runtime.h>
#include <cstdint>

// ECT loss: prediction [2,3,48,48,48] f32, target [2,48,48,48] int (0..2)
// out: scalar f32 loss.
//
// ws float layout:
//   [0..95]     dirs[3][32]   (unit directions, threefry-reproduced)
//   [96..159]   K[64] = exp(-8*lin[r])
//   [256..8447] gacc[4][2048] accumulators (bc*2048 + r*32 + d), bc=(b*2+c), c in {0,1}

#define P_TOT 110592
#define WS_K 96
#define WS_ACC 256

__device__ __forceinline__ uint32_t rotl32(uint32_t x, int d) {
  return (x << d) | (x >> (32 - d));
}

// threefry2x32 with key = (0, 17)  [jax.random.key(17)]
__device__ __forceinline__ void threefry_0_17(uint32_t x0, uint32_t x1,
                                              uint32_t& o0, uint32_t& o1) {
  const uint32_t ks0 = 0u, ks1 = 17u, ks2 = 0x1BD11BDAu ^ 0u ^ 17u;
  x0 += ks0; x1 += ks1;
#define R4(a,b,c,dd) \
  x0 += x1; x1 = rotl32(x1,(a)); x1 ^= x0; \
  x0 += x1; x1 = rotl32(x1,(b)); x1 ^= x0; \
  x0 += x1; x1 = rotl32(x1,(c)); x1 ^= x0; \
  x0 += x1; x1 = rotl32(x1,(dd)); x1 ^= x0;
  R4(13,15,26,6)   x0 += ks1; x1 += ks2 + 1u;
  R4(17,29,16,24)  x0 += ks2; x1 += ks0 + 2u;
  R4(13,15,26,6)   x0 += ks0; x1 += ks1 + 3u;
  R4(17,29,16,24)  x0 += ks1; x1 += ks2 + 4u;
  R4(13,15,26,6)   x0 += ks2; x1 += ks0 + 5u;
#undef R4
  o0 = x0; o1 = x1;
}

// XLA ErfInv32 (Giles polynomial)
__device__ __forceinline__ float erfinv_f32(float x) {
  float w = -log1pf(-x * x);
  float p;
  if (w < 5.0f) {
    w = w - 2.5f;
    p = 2.81022636e-08f;
    p = fmaf(p, w, 3.43273939e-07f);
    p = fmaf(p, w, -3.5233877e-06f);
    p = fmaf(p, w, -4.39150654e-06f);
    p = fmaf(p, w, 0.00021858087f);
    p = fmaf(p, w, -0.00125372503f);
    p = fmaf(p, w, -0.00417768164f);
    p = fmaf(p, w, 0.246640727f);
    p = fmaf(p, w, 1.50140941f);
  } else {
    w = sqrtf(w) - 3.0f;
    p = -0.000200214257f;
    p = fmaf(p, w, 0.000100950558f);
    p = fmaf(p, w, 0.00134934322f);
    p = fmaf(p, w, 0.000337081863f);
    p = fmaf(p, w, 0.00573950773f);
    p = fmaf(p, w, -0.0076224613f);
    p = fmaf(p, w, 0.00943887047f);
    p = fmaf(p, w, 1.00167406f);
    p = fmaf(p, w, 2.83297682f);
  }
  return p * x;
}

__global__ void ect_setup(float* __restrict__ ws) {
  __shared__ float normals[96];
  int t = threadIdx.x;
  if (t < 96) {
    // jax partitionable threefry bits: bits[i] = o0 ^ o1, ctr = (0, i)
    uint32_t o0, o1;
    threefry_0_17(0u, (uint32_t)t, o0, o1);
    uint32_t bits = o0 ^ o1;
    float u = __uint_as_float((bits >> 9) | 0x3F800000u) - 1.0f;  // [0,1)
    const float lo = -0.99999994f;                                // nextafter(-1,0)
    float v = fmaf(u, 2.0f, lo);   // u*(hi-lo)+lo, (hi-lo) rounds to 2.0f
    v = fmaxf(v, lo);
    normals[t] = 1.41421356237f * erfinv_f32(v);
  }
  __syncthreads();
  if (t < 32) {
    float a = normals[t], b = normals[32 + t], c = normals[64 + t];
    float n = fmaxf(sqrtf(a * a + b * b + c * c), 1e-12f);
    ws[t] = a / n; ws[32 + t] = b / n; ws[64 + t] = c / n;
  }
  if (t < 64) {
    const float radius = 1.1f * 1.7320508075688772f;  // 1.1*sqrt(3)
    const float step = (2.0f * radius) / 63.0f;
    float lin = fmaf((float)t, step, -radius);
    ws[WS_K + t] = expf(-8.0f * lin);
  }
  for (int i = t; i < 8192; i += 256) ws[WS_ACC + i] = 0.0f;
}

// Per chunk of NV voxels (per team of 256 threads):
//   phase A: 8x32 threads compute E[v][d] = exp(8*<coord,dir_d>); 32 threads compute dw
//   phase B: thread (d, rg) accumulates 8 r-values x 4 bc over the NV voxels
template <int NV>
__device__ __forceinline__ void do_chunk(
    int base, int team, int local, int d,
    float dir0, float dir1, float dir2, const float (&K)[8],
    const float* __restrict__ pred, const int* __restrict__ tgt,
    float (&E_lds)[4][256], float4 (&dw_lds)[4][8], float (&acc)[32]) {
  int v_role = local >> 5;
  if (v_role < NV) {
    int p = base + v_role;
    int ix = p / 2304; int rem = p - ix * 2304;
    int iy = rem / 48; int iz = rem - iy * 48;
    const float delta = 2.0f / 47.0f;
    float cx = (float)ix * delta - 1.0f;
    float cy = (float)iy * delta - 1.0f;
    float cz = (float)iz * delta - 1.0f;
    float nh = cx * dir0 + cy * dir1 + cz * dir2;
    E_lds[team][v_role * 32 + d] = __expf(8.0f * nh);
  }
  if (local < 4 * NV) {
    int vv = local >> 2, bc = local & 3;
    int b = bc >> 1, cc = bc & 1;
    int p = base + vv;
    const float* pb = pred + b * (3 * P_TOT) + p;
    float x0 = pb[0], x1 = pb[P_TOT], x2 = pb[2 * P_TOT];
    float m = fmaxf(x0, fmaxf(x1, x2));
    float e0 = __expf(x0 - m), e1 = __expf(x1 - m), e2 = __expf(x2 - m);
    float s = e0 + e1 + e2;
    float wv = ((cc == 0) ? e0 : e1) / s;
    int t = tgt[b * P_TOT + p];
    ((float*)&dw_lds[team][vv])[bc] = wv - ((t == cc) ? 1.0f : 0.0f);
  }
  __syncthreads();
#pragma unroll
  for (int v = 0; v < NV; v++) {
    float E = E_lds[team][v * 32 + d];
    float4 w = dw_lds[team][v];
#pragma unroll
    for (int j = 0; j < 8; j++) {
      float z = fmaf(E, K[j], 1.0f);           // 1 + e^{8 nh} e^{-8 lin_r}
      float sgm = __builtin_amdgcn_rcpf(z);    // sigmoid(8(lin_r - nh))
      acc[j * 4 + 0] = fmaf(w.x, sgm, acc[j * 4 + 0]);
      acc[j * 4 + 1] = fmaf(w.y, sgm, acc[j * 4 + 1]);
      acc[j * 4 + 2] = fmaf(w.z, sgm, acc[j * 4 + 2]);
      acc[j * 4 + 3] = fmaf(w.w, sgm, acc[j * 4 + 3]);
    }
  }
  __syncthreads();
}

__global__ __launch_bounds__(1024, 1) void ect_main(
    const float* __restrict__ pred, const int* __restrict__ tgt,
    const float* __restrict__ ws, float* __restrict__ gacc) {
  __shared__ float E_lds[4][256];
  __shared__ float4 dw_lds[4][8];
  __shared__ float acc_red[8192];

  int tid = threadIdx.x;
  int team = tid >> 8;
  int local = tid & 255;
  int d = local & 31;
  int rg = local >> 5;  // owns r = rg*8 .. rg*8+7

  float dir0 = ws[d], dir1 = ws[32 + d], dir2 = ws[64 + d];
  float K[8];
#pragma unroll
  for (int j = 0; j < 8; j++) K[j] = ws[WS_K + rg * 8 + j];

  float acc[32];
#pragma unroll
  for (int i = 0; i < 32; i++) acc[i] = 0.0f;

  int teamGlobal = blockIdx.x * 4 + team;
  int start = teamGlobal * 108;  // 256 blocks * 4 teams * 108 voxels = 110592

  for (int c = 0; c < 13; c++)
    do_chunk<8>(start + c * 8, team, local, d, dir0, dir1, dir2, K,
                pred, tgt, E_lds, dw_lds, acc);
  do_chunk<4>(start + 104, team, local, d, dir0, dir1, dir2, K,
              pred, tgt, E_lds, dw_lds, acc);

  // intra-block team reduction in LDS, then one global atomic set per block
  for (int i = tid; i < 8192; i += 1024) acc_red[i] = 0.0f;
  __syncthreads();
#pragma unroll
  for (int j = 0; j < 8; j++) {
    int r = rg * 8 + j;
#pragma unroll
    for (int bc = 0; bc < 4; bc++)
      atomicAdd(&acc_red[bc * 2048 + r * 32 + d], acc[j * 4 + bc]);
  }
  __syncthreads();
  for (int i = tid; i < 8192; i += 1024) atomicAdd(&gacc[i], acc_red[i]);
}

__global__ void ect_finalize(const float* __restrict__ gacc, float* __restrict__ out) {
  __shared__ float red[4];
  int t = threadIdx.x;
  float sum = 0.0f;
  // 4096 (b, rd) pairs; c=2 accumulator is -(c0+c1) since softmax and onehot both sum to 1
  for (int i = t; i < 4096; i += 256) {
    int b = i >> 11;
    int rd = i & 2047;
    float a0 = gacc[(b * 2 + 0) * 2048 + rd];
    float a1 = gacc[(b * 2 + 1) * 2048 + rd];
    float a2 = -(a0 + a1);
    sum += a0 * a0 + a1 * a1 + a2 * a2;
  }
#pragma unroll
  for (int off = 32; off > 0; off >>= 1) sum += __shfl_down(sum, off, 64);
  if ((t & 63) == 0) red[t >> 6] = sum;
  __syncthreads();
  if (t == 0) out[0] = (red[0] + red[1] + red[2] + red[3]) / 12288.0f;
}

extern "C" void kernel_launch(void* const* d_in, const int* in_sizes, int n_in,
                              void* d_out, int out_size, void* d_ws, size_t ws_size,
                              hipStream_t stream) {
  const float* pred = (const float*)d_in[0];
  const int* tgt = (const int*)d_in[1];
  float* ws = (float*)d_ws;
  float* out = (float*)d_out;

  hipLaunchKernelGGL(ect_setup, dim3(1), dim3(256), 0, stream, ws);
  hipLaunchKernelGGL(ect_main, dim3(256), dim3(1024), 0, stream,
                     pred, tgt, ws, ws + WS_ACC);
  hipLaunchKernelGGL(ect_finalize, dim3(1), dim3(256), 0, stream, ws + WS_ACC, out);
}